// Round 8
// baseline (245.245 us; speedup 1.0000x reference)
//
#include <hip/hip_runtime.h>

#define TOPK 10
#define CLIP 0.05f
#define EPSV 1e-8f
#define ALPHA1 2.0f
#define ALPHA_OTHER 0.5f
#define TCAND 2.5f     // candidate threshold; guarded by exact fallback in fix_kernel
#define MAXC 128       // per-row candidate capacity (mean ~60, sd ~8 at TCAND=2.5)

// sortable packed key: (monotone float key << 32) | (C - col)
// larger packed = larger value; on equal value, smaller col wins (matches lax.top_k)
__device__ __forceinline__ unsigned long long pack_vc(float v, int c, int C) {
  unsigned u = __float_as_uint(v);
  unsigned key = (u & 0x80000000u) ? ~u : (u | 0x80000000u);
  return ((unsigned long long)key << 32) | (unsigned)(C - c);
}
__device__ __forceinline__ float unpack_v(unsigned long long p) {
  unsigned key = (unsigned)(p >> 32);
  unsigned u = (key & 0x80000000u) ? (key & 0x7fffffffu) : ~key;
  return __uint_as_float(u);
}
__device__ __forceinline__ int unpack_c(unsigned long long p, int C) {
  return C - (int)(unsigned)(p & 0xffffffffu);
}

// base * w for one element. pos = (y == 1). Fast rcp avoids the full div sequence.
__device__ __forceinline__ float base_w(float xv, bool pos) {
  float e = __expf(-xv);
  float p = __builtin_amdgcn_rcpf(1.f + e);      // sigmoid
  float xneg = fminf(1.f - p + CLIP, 1.f);
  float q = pos ? p : xneg;
  float b = __logf(fmaxf(q, EPSV));
  float t = 1.f - q;                             // 1 - pt
  float t2 = t * t;
  float w = pos ? t : t2 * t2;                   // gamma: pos=1, neg=4
  return b * w;
}

__device__ __forceinline__ void push_cand(float v, long flat, int C, double invC,
                                          int* __restrict__ cnt,
                                          unsigned long long* __restrict__ cand,
                                          int maxc) {
  int row = (int)((double)flat * invC);
  int col = (int)(flat - (long)row * (long)C);
  if (col >= C) { row++; col -= C; }
  if (col < 0)  { row--; col += C; }
  int i = atomicAdd(&cnt[row], 1);
  if (i < maxc) cand[(long)row * maxc + i] = pack_vc(v, col, C);
}

// Kernel 1: copy-bench-shaped flat stream. Full occupancy (launch_bounds 256,8
// forces VGPR<=64 -> 8 waves/SIMD; grid 2048 = 8 blocks/CU, one dispatch round).
// Manual 2-deep register pipeline: load next float4 pair, compute current.
// Candidate detection = register bitmask; atomics deferred past the loop.
__global__ __launch_bounds__(256, 8) void stream_kernel(
    const float* __restrict__ x, const float* __restrict__ y,
    float* __restrict__ out, int* __restrict__ cnt,
    unsigned long long* __restrict__ cand, long N, int C, double invC, int maxc)
{
  const long N4 = N >> 2;
  const long S = (long)gridDim.x * 256;        // grid stride in float4 units
  const long gtid = (long)blockIdx.x * 256 + threadIdx.x;
  const float4* __restrict__ x4 = (const float4*)x;
  const float4* __restrict__ y4 = (const float4*)y;

  float4 acc = make_float4(0.f, 0.f, 0.f, 0.f);
  unsigned cmask = 0;
  float sum = 0.f;

  float4 Xc, Yc, Xn, Yn;
  long i = gtid;
  bool have = i < N4;
  if (have) { Xc = x4[i]; Yc = y4[i]; }
  int k = 0;
  while (have) {
    long nxt = i + S;
    bool have_n = nxt < N4;
    if (have_n) { Xn = x4[nxt]; Yn = y4[nxt]; }   // in flight during compute below
    acc.x += base_w(Xc.x, Yc.x > 0.5f);
    acc.y += base_w(Xc.y, Yc.y > 0.5f);
    acc.z += base_w(Xc.z, Yc.z > 0.5f);
    acc.w += base_w(Xc.w, Yc.w > 0.5f);
    float mx = fmaxf(fmaxf(Xc.x, Xc.y), fmaxf(Xc.z, Xc.w));
    cmask |= (mx > TCAND ? 1u : 0u) << k;
    k++;
    Xc = Xn; Yc = Yn; i = nxt; have = have_n;
  }
  sum = acc.x + acc.y + acc.z + acc.w;

  // materialize candidates (rare: ~0.06/thread; warm-cache reloads, off hot path)
  while (cmask) {
    int b = __ffs((int)cmask) - 1;
    cmask &= cmask - 1;
    long ii = gtid + (long)b * S;
    float4 X = x4[ii];
    long fb = ii << 2;
    if (X.x > TCAND) push_cand(X.x, fb + 0, C, invC, cnt, cand, maxc);
    if (X.y > TCAND) push_cand(X.y, fb + 1, C, invC, cnt, cand, maxc);
    if (X.z > TCAND) push_cand(X.z, fb + 2, C, invC, cnt, cand, maxc);
    if (X.w > TCAND) push_cand(X.w, fb + 3, C, invC, cnt, cand, maxc);
  }

  // scalar remainder (N % 4), handled by one thread
  if (gtid == 0) {
    for (long j = N4 * 4; j < N; j++) {
      float xv = x[j];
      sum += base_w(xv, y[j] > 0.5f);
      if (xv > TCAND) push_cand(xv, j, C, invC, cnt, cand, maxc);
    }
  }

  // block reduce -> one atomic
#pragma unroll
  for (int off = 32; off > 0; off >>= 1) sum += __shfl_xor(sum, off, 64);
  __shared__ float s_sum[4];
  const int lane = threadIdx.x & 63, wave = threadIdx.x >> 6;
  if (lane == 0) s_sum[wave] = sum;
  __syncthreads();
  if (threadIdx.x == 0)
    atomicAdd(out, -(s_sum[0] + s_sum[1] + s_sum[2] + s_sum[3]));
}

// Kernel 2: per-row top-10 + whitelist fixup. One block per row.
__global__ __launch_bounds__(256) void fix_kernel(
    const float* __restrict__ x, const float* __restrict__ y,
    const int* __restrict__ compost, const int* __restrict__ recycle,
    const int* __restrict__ donate, const int* __restrict__ wl_map,
    float* __restrict__ out, const int* __restrict__ cnt,
    const unsigned long long* __restrict__ cand,
    int C, int n1, int n2, int n3, int maxc)
{
  const int row = blockIdx.x;
  const float* xr = x + (size_t)row * (size_t)C;
  const float* yr = y + (size_t)row * (size_t)C;
  const int tid = threadIdx.x;
  const int lane = tid & 63;
  const int wave = tid >> 6;

  __shared__ int s_has[3];
  __shared__ unsigned long long s_top[TOPK];

  if (tid < 3) s_has[tid] = 0;
  __syncthreads();

  // waves 1-3: whitelist presence gathers (benign write-1 races)
  const int ntot = n1 + n2 + n3;
  if (wave > 0) {
    for (int i = tid - 64; i < ntot; i += 192) {
      int which, colI;
      if (i < n1)           { which = 0; colI = compost[i]; }
      else if (i < n1 + n2) { which = 1; colI = recycle[i - n1]; }
      else                  { which = 2; colI = donate[i - n1 - n2]; }
      if (yr[colI] > 0.5f) s_has[which] = 1;
    }
  }

  // wave 0: exact top-10
  if (wave == 0) {
    const int c = cnt[row];
    unsigned long long ls[TOPK];
#pragma unroll
    for (int s = 0; s < TOPK; s++) ls[s] = 0ULL;

#define INSERT(P)                                                          \
    do {                                                                   \
      unsigned long long _p = (P);                                         \
      if (_p > ls[TOPK - 1]) {                                             \
        _Pragma("unroll")                                                  \
        for (int _s = 0; _s < TOPK; _s++) {                                \
          bool _g = _p > ls[_s];                                           \
          unsigned long long _t = _g ? ls[_s] : _p;                        \
          ls[_s] = _g ? _p : ls[_s];                                       \
          _p = _t;                                                         \
        }                                                                  \
      }                                                                    \
    } while (0)

    if (c >= TOPK && c <= maxc) {
      const unsigned long long* cr = cand + (long)row * maxc;
      for (int i = lane; i < c; i += 64) INSERT(cr[i]);
    } else {
      // exact fallback: rescan the (L3-resident) row
      for (int col = lane; col < C; col += 64) INSERT(pack_vc(xr[col], col, C));
    }
#undef INSERT

    // 10 rounds of 64-lane packed max; pop winner (packed values unique)
    for (int r = 0; r < TOPK; r++) {
      unsigned long long mine = ls[0];
      unsigned long long best = mine;
#pragma unroll
      for (int off = 32; off > 0; off >>= 1) {
        unsigned long long o = __shfl_xor(best, off, 64);
        best = (o > best) ? o : best;
      }
      if (lane == 0) s_top[r] = best;
      if (mine == best) {
#pragma unroll
        for (int s = 0; s < TOPK - 1; s++) ls[s] = ls[s + 1];
        ls[TOPK - 1] = 0ULL;
      }
    }
  }
  __syncthreads();

  if (tid == 0) {
    const bool h1 = s_has[0] != 0, h2 = s_has[1] != 0, h3 = s_has[2] != 0;
    const bool gt4 = !(h1 || h2 || h3);

    // rank-sequential multiplier logic (mirrors the lax.scan)
    bool found = false;
    float fr[TOPK];
#pragma unroll
    for (int r = 0; r < TOPK; r++) {
      int col = unpack_c(s_top[r], C);
      int wl = wl_map[col];
      bool in_map = wl > 0;
      bool in_gt = (wl == 1 && h1) || (wl == 2 && h2) ||
                   (wl == 3 && h3) || (wl == 4 && gt4);
      float f = 1.f;
      if (in_map && gt4) f *= ALPHA_OTHER;
      if (in_map && !in_gt && !found) f *= ALPHA1;
      fr[r] = f;
      found = found || (in_map && in_gt);
    }
    const float extra = found ? 1.f : ALPHA1;
    float total = 0.f;
#pragma unroll
    for (int r = 0; r < TOPK; r++) {
      float mult = fr[r] * extra;
      if (mult != 1.f) {
        int col = unpack_c(s_top[r], C);
        float xv = unpack_v(s_top[r]);
        total += (mult - 1.f) * base_w(xv, yr[col] > 0.5f);
      }
    }
    if (total != 0.f) atomicAdd(out, -total);
  }
}

extern "C" void kernel_launch(void* const* d_in, const int* in_sizes, int n_in,
                              void* d_out, int out_size, void* d_ws, size_t ws_size,
                              hipStream_t stream) {
  const float* x       = (const float*)d_in[0];
  const float* y       = (const float*)d_in[1];
  const int*   compost = (const int*)d_in[2];
  const int*   recycle = (const int*)d_in[3];
  const int*   donate  = (const int*)d_in[4];
  const int*   wl_map  = (const int*)d_in[5];
  float* out = (float*)d_out;

  const int C  = in_sizes[5];
  const int B  = in_sizes[0] / C;
  const long N = (long)in_sizes[0];
  const int n1 = in_sizes[2], n2 = in_sizes[3], n3 = in_sizes[4];

  // workspace layout: [0, B*4) row counts; then 8-aligned candidate array
  size_t cand_off = ((size_t)B * 4 + 7) & ~(size_t)7;
  int maxc = MAXC;
  if (ws_size < cand_off + (size_t)B * maxc * 8) {
    size_t fit = (ws_size > cand_off) ? (ws_size - cand_off) / ((size_t)B * 8) : 0;
    maxc = (int)fit;  // maxc < TOPK simply forces the exact fallback path
  }
  int* cnt = (int*)d_ws;
  unsigned long long* cand = (unsigned long long*)((char*)d_ws + cand_off);
  double invC = 1.0 / (double)C;

  hipMemsetAsync(out, 0, sizeof(float), stream);
  hipMemsetAsync(cnt, 0, (size_t)B * 4, stream);
  // 2048 blocks = exactly 8 blocks/CU x 4 waves = 32 waves/CU (full residency),
  // single dispatch round; ~10 grid-stride iterations per thread
  stream_kernel<<<2048, 256, 0, stream>>>(x, y, out, cnt, cand, N, C, invC, maxc);
  fix_kernel<<<B, 256, 0, stream>>>(x, y, compost, recycle, donate, wl_map,
                                    out, cnt, cand, C, n1, n2, n3, maxc);
}